// Round 10
// baseline (249.413 us; speedup 1.0000x reference)
//
#include <hip/hip_runtime.h>
#include <hip/hip_bf16.h>
#include <stdint.h>

#define B_   4
#define T_   2048
#define D_   1024
#define H_   16
#define HD_  64
#define MROWS (B_*T_)      // 8192
#define NQKV  3072
#define NST  (T_/64)       // 32 s-tiles per head

typedef __attribute__((ext_vector_type(8))) short  short8;   // 8 x bf16
typedef __attribute__((ext_vector_type(4))) short  bf16x4;   // 4 x bf16 (avoid HIP's short4)
typedef __attribute__((ext_vector_type(4))) float  floatx4;

#define QSCALE 0.1803368801111244f   // log2(e)/sqrt(64)

__device__ inline void async_copy16(const __hip_bfloat16* g, __hip_bfloat16* l) {
  __builtin_amdgcn_global_load_lds(
      (const __attribute__((address_space(1))) void*)g,
      (__attribute__((address_space(3))) void*)l, 16, 0, 0);
}

// K=16 bf16 MFMA (gfx950: ..._16x16x16bf16_1k; fallback keeps it compiling)
__device__ inline floatx4 mfma16(bf16x4 a, bf16x4 b, floatx4 c) {
#if __has_builtin(__builtin_amdgcn_mfma_f32_16x16x16bf16_1k)
  return __builtin_amdgcn_mfma_f32_16x16x16bf16_1k(a, b, c, 0, 0, 0);
#elif __has_builtin(__builtin_amdgcn_mfma_f32_16x16x16_bf16)
  return __builtin_amdgcn_mfma_f32_16x16x16_bf16(a, b, c, 0, 0, 0);
#else
  short8 a8 = (short8){a[0], a[1], a[2], a[3], 0, 0, 0, 0};
  short8 b8 = (short8){b[0], b[1], b[2], b[3], 0, 0, 0, 0};
  return __builtin_amdgcn_mfma_f32_16x16x32_bf16(a8, b8, c, 0, 0, 0);
#endif
}

// ---------------- fused prep: convert x, convert Wo, transpose W{q,k,v} ----------------
// blocks [0,8192): x -> bf16 ; [8192,9216): Wo -> bf16 ; [9216,9984): transpose_w
__global__ void prep(const float* __restrict__ x, const float* __restrict__ Wo,
                     const float* __restrict__ Wq, const float* __restrict__ Wk,
                     const float* __restrict__ Wv,
                     __hip_bfloat16* __restrict__ xb, __hip_bfloat16* __restrict__ wob,
                     __hip_bfloat16* __restrict__ wqkv) {
  __shared__ __hip_bfloat16 tile[64][65];
  const int bid = (int)blockIdx.x;
  const int t = threadIdx.x;
  if (bid < 8192) {                      // convert x (8.39M elems)
    int i = (bid * 256 + t) * 4;
    float4 v = *(const float4*)(x + i);
    xb[i + 0] = __float2bfloat16(v.x);
    xb[i + 1] = __float2bfloat16(v.y);
    xb[i + 2] = __float2bfloat16(v.z);
    xb[i + 3] = __float2bfloat16(v.w);
  } else if (bid < 9216) {               // convert Wo (1.05M elems)
    int i = ((bid - 8192) * 256 + t) * 4;
    float4 v = *(const float4*)(Wo + i);
    wob[i + 0] = __float2bfloat16(v.x);
    wob[i + 1] = __float2bfloat16(v.y);
    wob[i + 2] = __float2bfloat16(v.z);
    wob[i + 3] = __float2bfloat16(v.w);
  } else {                               // transpose W
    int idx = bid - 9216;
    const int d0 = (idx & 15) * 64;
    const int wh = idx >> 4;             // 0..47
    const int which = wh >> 4, h = wh & 15;
    const float* W = (which == 0) ? Wq : ((which == 1) ? Wk : Wv);
    const float* base = W + (size_t)h * D_ * HD_;
#pragma unroll
    for (int i = 0; i < 16; i++) {
      int e = i * 256 + t;
      int dr = e >> 6, hd = e & 63;
      tile[dr][hd] = __float2bfloat16(base[(size_t)(d0 + dr) * HD_ + hd]);
    }
    __syncthreads();
#pragma unroll
    for (int i = 0; i < 16; i++) {
      int e = i * 256 + t;
      int hd = e >> 6, dr = e & 63;
      wqkv[(size_t)(which * 1024 + h * 64 + hd) * D_ + d0 + dr] = tile[dr][hd];
    }
  }
}

// ---------------- repack K,V into fragment-contiguous tiles ----------------
__global__ void repack_kv(const __hip_bfloat16* __restrict__ qkv,
                          __hip_bfloat16* __restrict__ kpack, __hip_bfloat16* __restrict__ vpack) {
  __shared__ __hip_bfloat16 Ks[64][72];
  __shared__ __hip_bfloat16 Vs[64][72];
  const int tid = threadIdx.x;
  const int st = blockIdx.x, bh = blockIdx.y;
  const int b = bh >> 4, h = bh & 15;
#pragma unroll
  for (int p = 0; p < 2; p++) {
    int c = p * 256 + tid;           // 512 chunks of 16B per matrix
    int row = c >> 3, col8 = c & 7;
    const __hip_bfloat16* src = qkv + (size_t)(b * T_ + st * 64 + row) * NQKV + h * HD_ + col8 * 8;
    *(uint4*)&Ks[row][col8 * 8] = *(const uint4*)(src + 1024);
    *(uint4*)&Vs[row][col8 * 8] = *(const uint4*)(src + 2048);
  }
  __syncthreads();
  const size_t base = ((size_t)bh * NST + st) * 8 * 512;
#pragma unroll
  for (int p = 0; p < 2; p++) {
    int pair = p * 256 + tid;        // 8 chunks x 64 lanes
    int c = pair >> 6, l = pair & 63;
    int lq = l & 15, q = l >> 4;
    int ni = c >> 1, half = c & 1;
    short8 v = *(const short8*)&Ks[ni * 16 + lq][half * 32 + q * 8];
    *(short8*)(kpack + base + (size_t)c * 512 + l * 8) = v;
  }
#pragma unroll
  for (int p = 0; p < 2; p++) {
    int pair = p * 256 + tid;
    int c = pair >> 6, l = pair & 63;
    int lq = l & 15, q = l >> 4;
    int m = c >> 2, nt = c & 3;
    __hip_bfloat16 tmp[8];
#pragma unroll
    for (int half = 0; half < 2; half++)
#pragma unroll
      for (int j = 0; j < 4; j++)
        tmp[half * 4 + j] = Vs[(2 * m + half) * 16 + q * 4 + j][nt * 16 + lq];
    *(short8*)(vpack + base + (size_t)c * 512 + l * 8) = *(short8*)tmp;
  }
}

// ---------------- shared GEMM staging helpers (T2 swizzle pair, 0 conflicts measured) ----------------

__device__ inline void stage16k(const __hip_bfloat16* __restrict__ grow0, int K,
                                short* ldst, int tid) {
  // one 16KB unit = 128 rows x 64 cols bf16; 1024 chunks of 16B, 2/thread (512 thr)
#pragma unroll
  for (int l = 0; l < 2; ++l) {
    int c = l * 512 + tid;
    int r = c >> 3;                          // LDS row 0..127
    int sw = (c & 7) ^ (r & 7);              // pre-swizzled source slot
    async_copy16(grow0 + (size_t)r * K + sw * 8, (__hip_bfloat16*)(ldst + c * 8));
  }
}

__device__ inline short8 fragld2(const short* base, int r, int slot) {
  return *(const short8*)(base + r * 64 + (((slot) ^ (r & 7)) << 3));
}

// ---------------- QKV GEMM: 128x384 tile, BK=64, single-segment K-step ----------------
// (validated round 6: dropped out of top-5, <60 us from 70)
__launch_bounds__(512, 2)
__global__ void gemmq(const __hip_bfloat16* __restrict__ A, const __hip_bfloat16* __restrict__ Bt,
                      __hip_bfloat16* __restrict__ Cb, int M, int N, int K, float qscale) {
  // per buffer: A[128][64] = 8192 shorts | B[384][64] = 24576 shorts  (64 KB)
  __shared__ short LDS[2][32768];            // 128 KB total
  const int tid = threadIdx.x;
  const int lane = tid & 63, wid = tid >> 6;
  const int lq = lane & 15, quad = lane >> 4;
  const int wr = wid >> 2, wc = wid & 3;     // 2 x 4 waves, wave-tile 64 x 96

  // n-major XCD chunking: lin%8 = XCD owns one n-panel; m-panels stream within.
  const int lin = (int)blockIdx.x;
  const int s = (lin & 7) * 64 + (lin >> 3); // bijection on [0,512)
  const int m0 = (s & 63) * 128, n0 = (s >> 6) * 384;

  const int NT = K >> 6;                     // 16

  floatx4 acc[4][6];
#pragma unroll
  for (int i = 0; i < 4; i++)
#pragma unroll
    for (int j = 0; j < 6; j++) acc[i][j] = (floatx4){0.f, 0.f, 0.f, 0.f};

  // prologue: stage tile 0 (A unit + 3 B units, 8 loads/thread)
  {
    short* b0 = &LDS[0][0];
    stage16k(A + (size_t)m0 * K, K, b0, tid);
#pragma unroll
    for (int j = 0; j < 3; ++j)
      stage16k(Bt + (size_t)(n0 + 128 * j) * K, K, b0 + 8192 + 8192 * j, tid);
  }

#pragma unroll 1
  for (int t = 0; t < NT; ++t) {
    __syncthreads();                         // drains vmcnt(0): tile t landed (issued a full segment ago)
    const short* buf = &LDS[t & 1][0];
    short* nb = &LDS[(t & 1) ^ 1][0];
    const int kc = (t + 1) << 6;

    // ---- kk = 0: reads + stage-issue + 24 MFMA ----
    short8 a0[4], b0[6];
#pragma unroll
    for (int mi = 0; mi < 4; ++mi)
      a0[mi] = fragld2(buf, wr * 64 + mi * 16 + lq, quad);
#pragma unroll
    for (int ni = 0; ni < 6; ++ni)
      b0[ni] = fragld2(buf + 8192, wc * 96 + ni * 16 + lq, quad);
    if (t + 1 < NT) {                        // stage tile t+1 -> other buffer
      stage16k(A + (size_t)m0 * K + kc, K, nb, tid);
#pragma unroll
      for (int j = 0; j < 3; ++j)
        stage16k(Bt + (size_t)(n0 + 128 * j) * K + kc, K, nb + 8192 + 8192 * j, tid);
    }
    __builtin_amdgcn_s_setprio(1);
#pragma unroll
    for (int mi = 0; mi < 4; ++mi)
#pragma unroll
      for (int ni = 0; ni < 6; ++ni)
        acc[mi][ni] = __builtin_amdgcn_mfma_f32_16x16x32_bf16(a0[mi], b0[ni], acc[mi][ni], 0, 0, 0);
    __builtin_amdgcn_s_setprio(0);

    // ---- kk = 1: reads + 24 MFMA ----
    short8 a1[4], b1[6];
#pragma unroll
    for (int mi = 0; mi < 4; ++mi)
      a1[mi] = fragld2(buf, wr * 64 + mi * 16 + lq, 4 + quad);
#pragma unroll
    for (int ni = 0; ni < 6; ++ni)
      b1[ni] = fragld2(buf + 8192, wc * 96 + ni * 16 + lq, 4 + quad);
    __builtin_amdgcn_s_setprio(1);
#pragma unroll
    for (int mi = 0; mi < 4; ++mi)
#pragma unroll
      for (int ni = 0; ni < 6; ++ni)
        acc[mi][ni] = __builtin_amdgcn_mfma_f32_16x16x32_bf16(a1[mi], b1[ni], acc[mi][ni], 0, 0, 0);
    __builtin_amdgcn_s_setprio(0);
  }

  // epilogue: bf16 store, q-columns pre-scaled by log2e/sqrt(64)
#pragma unroll
  for (int mi = 0; mi < 4; ++mi) {
#pragma unroll
    for (int ni = 0; ni < 6; ++ni) {
      int col = n0 + wc * 96 + ni * 16 + lq;
      float sc = (col < 1024) ? qscale : 1.0f;
#pragma unroll
      for (int r = 0; r < 4; ++r) {
        int row = m0 + wr * 64 + mi * 16 + quad * 4 + r;
        Cb[(size_t)row * N + col] = __float2bfloat16(acc[mi][ni][r] * sc);
      }
    }
  }
}

// ---------------- GEMM: C = A[M,K] * Bt[N,K]^T (output projection — restored, gemmo regressed) ----------------
template <int EPI>
__launch_bounds__(256, 2)
__global__ void gemm_bt(const __hip_bfloat16* __restrict__ A, const __hip_bfloat16* __restrict__ Bt,
                        __hip_bfloat16* __restrict__ Cb, float* __restrict__ Cf,
                        const float* __restrict__ bias, int M, int N, int K, float qscale) {
  __shared__ __hip_bfloat16 As[128 * 32];
  __shared__ __hip_bfloat16 Bs[128 * 32];
  const int tid = threadIdx.x;
  const int w = tid >> 6, lane = tid & 63;
  const int lq = lane & 15, quad = lane >> 4;
  const int wr = w >> 1, wc = w & 1;
  const int m0 = blockIdx.x * 128, n0 = blockIdx.y * 128;

  floatx4 acc[4][4];
#pragma unroll
  for (int i = 0; i < 4; i++)
#pragma unroll
    for (int j = 0; j < 4; j++) acc[i][j] = (floatx4){0.f, 0.f, 0.f, 0.f};

  for (int k0 = 0; k0 < K; k0 += 32) {
    __syncthreads();
#pragma unroll
    for (int ph = 0; ph < 2; ++ph) {
      int c = ph * 256 + tid;
      int row = c >> 2, col8 = c & 3;
      async_copy16(A + (size_t)(m0 + row) * K + k0 + col8 * 8, As + c * 8);
      async_copy16(Bt + (size_t)(n0 + row) * K + k0 + col8 * 8, Bs + c * 8);
    }
    __syncthreads();
    short8 af[4], bf[4];
#pragma unroll
    for (int mi = 0; mi < 4; mi++)
      af[mi] = *(const short8*)(As + (wr * 64 + mi * 16 + lq) * 32 + quad * 8);
#pragma unroll
    for (int ni = 0; ni < 4; ni++)
      bf[ni] = *(const short8*)(Bs + (wc * 64 + ni * 16 + lq) * 32 + quad * 8);
#pragma unroll
    for (int mi = 0; mi < 4; mi++)
#pragma unroll
      for (int ni = 0; ni < 4; ni++)
        acc[mi][ni] = __builtin_amdgcn_mfma_f32_16x16x32_bf16(af[mi], bf[ni], acc[mi][ni], 0, 0, 0);
  }

#pragma unroll
  for (int mi = 0; mi < 4; mi++) {
#pragma unroll
    for (int ni = 0; ni < 4; ni++) {
      int col = n0 + wc * 64 + ni * 16 + lq;
      if (EPI == 0) {
        float s = (col < 1024) ? qscale : 1.0f;
#pragma unroll
        for (int r = 0; r < 4; r++) {
          int row = m0 + wr * 64 + mi * 16 + quad * 4 + r;
          Cb[(size_t)row * N + col] = __float2bfloat16(acc[mi][ni][r] * s);
        }
      } else {
        float bv = bias[col];
#pragma unroll
        for (int r = 0; r < 4; r++) {
          int row = m0 + wr * 64 + mi * 16 + quad * 4 + r;
          Cf[(size_t)row * N + col] = acc[mi][ni][r] + bv;
        }
      }
    }
  }
}

// ---------------- flash attention: 3-deep LDS rotation, counted vmcnt (gemmk-proven pattern) ----------------
// Grid (64 bh, 8) unchanged (proven). The round-6 __syncthreads drained vmcnt(0)
// every iteration, synchronously eating the L2 latency of loads issued that same
// iteration. Now: stage tile t+2 into a 3-buffer rotation; boundary waits only
// vmcnt(4) (drains t+1, leaves t+2 in flight) + raw s_barrier. Issue-to-use = 2
// iterations. Per-thread ledger: prologue 8 -> vmcnt(4); steady 4+4 -> vmcnt(4);
// tail vmcnt(0); last iter nothing in flight. All barriers unconditional.
__launch_bounds__(256, 2)
__global__ void attn(const __hip_bfloat16* __restrict__ qkv,
                     const __hip_bfloat16* __restrict__ kpack,
                     const __hip_bfloat16* __restrict__ vpack,
                     __hip_bfloat16* __restrict__ obuf) {
  __shared__ __hip_bfloat16 KVs[3][8192];    // [buf][K:0..4095 | V:4096..8191], 48 KB
  const int tid = threadIdx.x;
  const int w = tid >> 6, lane = tid & 63;
  const int lq = lane & 15, quad = lane >> 4;

  const int bh = (int)blockIdx.x;            // XCD = bh % 8
  const int a  = (int)blockIdx.y;            // 0..7
  const int b = bh >> 4, h = bh & 15;

  const __hip_bfloat16* kbase = kpack + ((size_t)bh * NST) * 4096;
  const __hip_bfloat16* vbase = vpack + ((size_t)bh * NST) * 4096;

#pragma unroll 1
  for (int seg = 0; seg < 2; ++seg) {
    const int tbase = seg ? (NST - 2 - 2 * a) : (2 * a);
    const int qt = tbase + (w >> 1);         // this wave's q-tile
    const int rbase = (w & 1) * 32;          // row base within tile

    short8 qf[2][2];
#pragma unroll
    for (int bi = 0; bi < 2; bi++) {
      const __hip_bfloat16* qp =
          qkv + ((size_t)(b * T_ + qt * 64 + rbase + bi * 16 + lq)) * NQKV + h * HD_;
      qf[bi][0] = *(const short8*)(qp + quad * 8);
      qf[bi][1] = *(const short8*)(qp + 32 + quad * 8);
    }

    floatx4 Oacc[2][4];
#pragma unroll
    for (int bi = 0; bi < 2; bi++)
#pragma unroll
      for (int i = 0; i < 4; i++) Oacc[bi][i] = (floatx4){0.f, 0.f, 0.f, 0.f};
    float lrow[2] = {0.f, 0.f};

    const int itTop = tbase + 1;             // block iterates tiles 0..itTop (itTop >= 1)

    // prologue: stage tiles 0 and 1 (8 loads/thread); drain tile 0, keep tile 1 in flight
#pragma unroll
    for (int j = 0; j < 2; ++j) {
      int c = j * 256 + tid;
      async_copy16(kbase + (size_t)c * 8, &KVs[0][0] + c * 8);
      async_copy16(vbase + (size_t)c * 8, &KVs[0][4096] + c * 8);
    }
#pragma unroll
    for (int j = 0; j < 2; ++j) {
      int c = j * 256 + tid;
      async_copy16(kbase + 4096 + (size_t)c * 8, &KVs[1][0] + c * 8);
      async_copy16(vbase + 4096 + (size_t)c * 8, &KVs[1][4096] + c * 8);
    }
    asm volatile("s_waitcnt vmcnt(4)" ::: "memory");
    __builtin_amdgcn_s_barrier();

    int cur = 0;
#pragma unroll 1
    for (int it = 0; it <= itTop; ++it) {
      if (it + 2 <= itTop) {                 // stage tile it+2 into the free buffer
        int nb = cur + 2; if (nb >= 3) nb -= 3;
        const __hip_bfloat16* kn = kbase + (size_t)(it + 2) * 4096;
        const __hip_bfloat16* vn = vbase + (size_t)(it + 2) * 4096;
#pragma unroll
        for (int j = 0; j < 2; ++j) {
          int c = j * 256 + tid;
          async_copy16(kn + (size_t)c * 8, &KVs[nb][0] + c * 8);
          async_copy16(vn + (size_t)c * 8, &KVs[nb][4096] + c * 8);
        }
      }
      if (it <= qt) {                        // wave-uniform predicate (no barriers inside)
        const __hip_bfloat16* Kb = &KVs[cur][0] + lane * 8;
        const __hip_bfloat16* Vb = &KVs[cur][4096] + lane * 8;
        short8 kf[4], kg[4];
#pragma unroll
        for (int ni = 0; ni < 4; ni++) {
          kf[ni] = *(const short8*)(Kb + (size_t)(ni * 2 + 0) * 512);
          kg[ni] = *(const short8*)(Kb + (size_t)(ni * 2 + 1) * 512);
        }
        short8 vfr[8];
#pragma unroll
        for (int c = 0; c < 8; c++) vfr[c] = *(const short8*)(Vb + (size_t)c * 512);

        floatx4 Sc[2][4];
        __builtin_amdgcn_s_setprio(1);
#pragma unroll
        for (int bi = 0; bi < 2; bi++)
#pragma unroll
          for (int ni = 0; ni < 4; ni++) {
            floatx4 c0 = (floatx4){0.f, 0.f, 0.f, 0.f};
            c0 = __builtin_amdgcn_mfma_f32_16x16x32_bf16(kf[ni], qf[bi][0], c0, 0, 0, 0);
            c0 = __builtin_amdgcn_mfma_f32_16x16x32_bf16(kg[ni], qf[bi][1], c0, 0, 0, 0);
            Sc[bi][ni] = c0;
          }
        __builtin_amdgcn_s_setprio(0);

        if (it == qt) {
#pragma unroll
          for (int bi = 0; bi < 2; bi++) {
            int lrow_idx = rbase + bi * 16 + lq;
#pragma unroll
            for (int ni = 0; ni < 4; ni++)
#pragma unroll
              for (int r = 0; r < 4; r++) {
                int s_loc = ni * 16 + quad * 4 + r;
                if (s_loc > lrow_idx) Sc[bi][ni][r] = -__builtin_inff();
              }
          }
        }

        bf16x4 pf[2][4];
#pragma unroll
        for (int bi = 0; bi < 2; bi++)
#pragma unroll
          for (int c = 0; c < 4; c++) {
            __hip_bfloat16 pb[4];
#pragma unroll
            for (int r = 0; r < 4; r++) {
              float p = __builtin_amdgcn_exp2f(Sc[bi][c][r]);
              lrow[bi] += p;
              pb[r] = __float2bfloat16(p);
            }
            pf[bi][c] = *(bf16x4*)pb;
          }

        __builtin_amdgcn_s_setprio(1);
#pragma unroll
        for (int m = 0; m < 2; m++)
#pragma unroll
          for (int nt = 0; nt < 4; nt++) {
            short8 v8 = vfr[m * 4 + nt];
            bf16x4 vlo = (bf16x4){v8[0], v8[1], v8[2], v8[3]};
            bf16x4 vhi = (bf16x4){v8[4], v8[5], v8[6], v8[7]};
#pragma unroll
            for (int bi = 0; bi < 2; bi++) {
              Oacc[bi][nt] = mfma16(pf[bi][2 * m + 0], vlo, Oacc[bi][nt]);
              Oacc[bi][nt] = mfma16(pf[bi][2 * m + 1], vhi, Oacc[bi][nt]);
            }
          }
        __builtin_amdgcn_s_setprio(0);
      }
      // boundary: drain tile it+1 (next iter's input); keep tile it+2 in flight
      if (it + 1 <= itTop) {
        if (it + 2 <= itTop) { asm volatile("s_waitcnt vmcnt(4)" ::: "memory"); }
        else                 { asm volatile("s_waitcnt vmcnt(0)" ::: "memory"); }
      }
      __builtin_amdgcn_s_barrier();
      cur += 1; if (cur == 3) cur = 0;
    }

    // epilogue per band: reduce lrow across quads, normalize, store
#pragma unroll
    for (int bi = 0; bi < 2; bi++) {
      float ps = lrow[bi];
      ps += __shfl_xor(ps, 16);
      ps += __shfl_xor(ps, 32);
      float inv = 1.0f / ps;
#pragma unroll
      for (int r = 0; r < 4; r++) {
        float invr = __shfl(inv, quad * 4 + r);
        int t = qt * 64 + rbase + bi * 16 + quad * 4 + r;
#pragma unroll
        for (int nt = 0; nt < 4; nt++)
          obuf[(size_t)(b * T_ + t) * D_ + h * HD_ + nt * 16 + lq] =
              __float2bfloat16(Oacc[bi][nt][r] * invr);
      }
    }
  }
}

// ---------------- launch ----------------

extern "C" void kernel_launch(void* const* d_in, const int* in_sizes, int n_in,
                              void* d_out, int out_size, void* d_ws, size_t ws_size,
                              hipStream_t stream) {
  const float* x  = (const float*)d_in[0];
  const float* Wq = (const float*)d_in[1];
  const float* Wk = (const float*)d_in[2];
  const float* Wv = (const float*)d_in[3];
  const float* Wo = (const float*)d_in[4];
  const float* bo = (const float*)d_in[5];
  float* out = (float*)d_out;

  char* ws = (char*)d_ws;
  __hip_bfloat16* xb    = (__hip_bfloat16*)(ws);                          // 16 MB (dead after QKV gemm)
  __hip_bfloat16* obuf  = (__hip_bfloat16*)(ws);                          // reuses xb's slot
  __hip_bfloat16* wqkv  = (__hip_bfloat16*)(ws + ((size_t)16 << 20));     //  6 MB
  __hip_bfloat16* wob   = (__hip_bfloat16*)(ws + ((size_t)22 << 20));     //  2 MB
  __hip_bfloat16* qkv   = (__hip_bfloat16*)(ws + ((size_t)24 << 20));     // 48 MB
  __hip_bfloat16* kpack = (__hip_bfloat16*)(ws + ((size_t)72 << 20));     // 16 MB
  __hip_bfloat16* vpack = (__hip_bfloat16*)(ws + ((size_t)88 << 20));     // 16 MB

  prep<<<9984, 256, 0, stream>>>(x, Wo, Wq, Wk, Wv, xb, wob, wqkv);

  // qkv = xb * wqkv^T   (q columns pre-scaled by log2e/8) — 128x384 single-segment kernel
  gemmq<<<512, 512, 0, stream>>>(xb, wqkv, qkv, MROWS, NQKV, D_, QSCALE);

  repack_kv<<<dim3(NST, B_ * H_), 256, 0, stream>>>(qkv, kpack, vpack);

  attn<<<dim3(B_ * H_, 8), 256, 0, stream>>>(qkv, kpack, vpack, obuf);

  // out = obuf * Wo^T + bo — proven gemm_bt<1> (gemmo reverted: −10 us regression)
  gemm_bt<1><<<dim3(MROWS / 128, D_ / 128), 256, 0, stream>>>(
      obuf, wob, nullptr, out, bo, MROWS, D_, D_, 1.0f);
}

// Round 11
// 233.659 us; speedup vs baseline: 1.0674x; 1.0674x over previous
//
#include <hip/hip_runtime.h>
#include <hip/hip_bf16.h>
#include <stdint.h>

#define B_   4
#define T_   2048
#define D_   1024
#define H_   16
#define HD_  64
#define MROWS (B_*T_)      // 8192
#define NQKV  3072
#define NST  (T_/64)       // 32 s-tiles per head

typedef __attribute__((ext_vector_type(8))) short  short8;   // 8 x bf16
typedef __attribute__((ext_vector_type(4))) short  bf16x4;   // 4 x bf16 (avoid HIP's short4)
typedef __attribute__((ext_vector_type(4))) float  floatx4;

#define QSCALE 0.1803368801111244f   // log2(e)/sqrt(64)

__device__ inline void async_copy16(const __hip_bfloat16* g, __hip_bfloat16* l) {
  __builtin_amdgcn_global_load_lds(
      (const __attribute__((address_space(1))) void*)g,
      (__attribute__((address_space(3))) void*)l, 16, 0, 0);
}

// K=16 bf16 MFMA (gfx950: ..._16x16x16bf16_1k; fallback keeps it compiling)
__device__ inline floatx4 mfma16(bf16x4 a, bf16x4 b, floatx4 c) {
#if __has_builtin(__builtin_amdgcn_mfma_f32_16x16x16bf16_1k)
  return __builtin_amdgcn_mfma_f32_16x16x16bf16_1k(a, b, c, 0, 0, 0);
#elif __has_builtin(__builtin_amdgcn_mfma_f32_16x16x16_bf16)
  return __builtin_amdgcn_mfma_f32_16x16x16_bf16(a, b, c, 0, 0, 0);
#else
  short8 a8 = (short8){a[0], a[1], a[2], a[3], 0, 0, 0, 0};
  short8 b8 = (short8){b[0], b[1], b[2], b[3], 0, 0, 0, 0};
  return __builtin_amdgcn_mfma_f32_16x16x32_bf16(a8, b8, c, 0, 0, 0);
#endif
}

// ---------------- fused prep: convert x, convert Wo, transpose W{q,k,v} ----------------
// blocks [0,8192): x -> bf16 ; [8192,9216): Wo -> bf16 ; [9216,9984): transpose_w
__global__ void prep(const float* __restrict__ x, const float* __restrict__ Wo,
                     const float* __restrict__ Wq, const float* __restrict__ Wk,
                     const float* __restrict__ Wv,
                     __hip_bfloat16* __restrict__ xb, __hip_bfloat16* __restrict__ wob,
                     __hip_bfloat16* __restrict__ wqkv) {
  __shared__ __hip_bfloat16 tile[64][65];
  const int bid = (int)blockIdx.x;
  const int t = threadIdx.x;
  if (bid < 8192) {                      // convert x (8.39M elems)
    int i = (bid * 256 + t) * 4;
    float4 v = *(const float4*)(x + i);
    xb[i + 0] = __float2bfloat16(v.x);
    xb[i + 1] = __float2bfloat16(v.y);
    xb[i + 2] = __float2bfloat16(v.z);
    xb[i + 3] = __float2bfloat16(v.w);
  } else if (bid < 9216) {               // convert Wo (1.05M elems)
    int i = ((bid - 8192) * 256 + t) * 4;
    float4 v = *(const float4*)(Wo + i);
    wob[i + 0] = __float2bfloat16(v.x);
    wob[i + 1] = __float2bfloat16(v.y);
    wob[i + 2] = __float2bfloat16(v.z);
    wob[i + 3] = __float2bfloat16(v.w);
  } else {                               // transpose W
    int idx = bid - 9216;
    const int d0 = (idx & 15) * 64;
    const int wh = idx >> 4;             // 0..47
    const int which = wh >> 4, h = wh & 15;
    const float* W = (which == 0) ? Wq : ((which == 1) ? Wk : Wv);
    const float* base = W + (size_t)h * D_ * HD_;
#pragma unroll
    for (int i = 0; i < 16; i++) {
      int e = i * 256 + t;
      int dr = e >> 6, hd = e & 63;
      tile[dr][hd] = __float2bfloat16(base[(size_t)(d0 + dr) * HD_ + hd]);
    }
    __syncthreads();
#pragma unroll
    for (int i = 0; i < 16; i++) {
      int e = i * 256 + t;
      int hd = e >> 6, dr = e & 63;
      wqkv[(size_t)(which * 1024 + h * 64 + hd) * D_ + d0 + dr] = tile[dr][hd];
    }
  }
}

// ---------------- repack K,V into fragment-contiguous tiles ----------------
__global__ void repack_kv(const __hip_bfloat16* __restrict__ qkv,
                          __hip_bfloat16* __restrict__ kpack, __hip_bfloat16* __restrict__ vpack) {
  __shared__ __hip_bfloat16 Ks[64][72];
  __shared__ __hip_bfloat16 Vs[64][72];
  const int tid = threadIdx.x;
  const int st = blockIdx.x, bh = blockIdx.y;
  const int b = bh >> 4, h = bh & 15;
#pragma unroll
  for (int p = 0; p < 2; p++) {
    int c = p * 256 + tid;           // 512 chunks of 16B per matrix
    int row = c >> 3, col8 = c & 7;
    const __hip_bfloat16* src = qkv + (size_t)(b * T_ + st * 64 + row) * NQKV + h * HD_ + col8 * 8;
    *(uint4*)&Ks[row][col8 * 8] = *(const uint4*)(src + 1024);
    *(uint4*)&Vs[row][col8 * 8] = *(const uint4*)(src + 2048);
  }
  __syncthreads();
  const size_t base = ((size_t)bh * NST + st) * 8 * 512;
#pragma unroll
  for (int p = 0; p < 2; p++) {
    int pair = p * 256 + tid;        // 8 chunks x 64 lanes
    int c = pair >> 6, l = pair & 63;
    int lq = l & 15, q = l >> 4;
    int ni = c >> 1, half = c & 1;
    short8 v = *(const short8*)&Ks[ni * 16 + lq][half * 32 + q * 8];
    *(short8*)(kpack + base + (size_t)c * 512 + l * 8) = v;
  }
#pragma unroll
  for (int p = 0; p < 2; p++) {
    int pair = p * 256 + tid;
    int c = pair >> 6, l = pair & 63;
    int lq = l & 15, q = l >> 4;
    int m = c >> 2, nt = c & 3;
    __hip_bfloat16 tmp[8];
#pragma unroll
    for (int half = 0; half < 2; half++)
#pragma unroll
      for (int j = 0; j < 4; j++)
        tmp[half * 4 + j] = Vs[(2 * m + half) * 16 + q * 4 + j][nt * 16 + lq];
    *(short8*)(vpack + base + (size_t)c * 512 + l * 8) = *(short8*)tmp;
  }
}

// ---------------- shared GEMM staging helpers (T2 swizzle pair, 0 conflicts measured) ----------------

__device__ inline void stage16k(const __hip_bfloat16* __restrict__ grow0, int K,
                                short* ldst, int tid) {
  // one 16KB unit = 128 rows x 64 cols bf16; 1024 chunks of 16B, 2/thread (512 thr)
#pragma unroll
  for (int l = 0; l < 2; ++l) {
    int c = l * 512 + tid;
    int r = c >> 3;                          // LDS row 0..127
    int sw = (c & 7) ^ (r & 7);              // pre-swizzled source slot
    async_copy16(grow0 + (size_t)r * K + sw * 8, (__hip_bfloat16*)(ldst + c * 8));
  }
}

__device__ inline short8 fragld2(const short* base, int r, int slot) {
  return *(const short8*)(base + r * 64 + (((slot) ^ (r & 7)) << 3));
}

// ---------------- QKV GEMM: 128x384 tile, BK=64, single-segment K-step ----------------
// (validated round 6: dropped out of top-5, <60 us from 70)
__launch_bounds__(512, 2)
__global__ void gemmq(const __hip_bfloat16* __restrict__ A, const __hip_bfloat16* __restrict__ Bt,
                      __hip_bfloat16* __restrict__ Cb, int M, int N, int K, float qscale) {
  // per buffer: A[128][64] = 8192 shorts | B[384][64] = 24576 shorts  (64 KB)
  __shared__ short LDS[2][32768];            // 128 KB total
  const int tid = threadIdx.x;
  const int lane = tid & 63, wid = tid >> 6;
  const int lq = lane & 15, quad = lane >> 4;
  const int wr = wid >> 2, wc = wid & 3;     // 2 x 4 waves, wave-tile 64 x 96

  // n-major XCD chunking: lin%8 = XCD owns one n-panel; m-panels stream within.
  const int lin = (int)blockIdx.x;
  const int s = (lin & 7) * 64 + (lin >> 3); // bijection on [0,512)
  const int m0 = (s & 63) * 128, n0 = (s >> 6) * 384;

  const int NT = K >> 6;                     // 16

  floatx4 acc[4][6];
#pragma unroll
  for (int i = 0; i < 4; i++)
#pragma unroll
    for (int j = 0; j < 6; j++) acc[i][j] = (floatx4){0.f, 0.f, 0.f, 0.f};

  // prologue: stage tile 0 (A unit + 3 B units, 8 loads/thread)
  {
    short* b0 = &LDS[0][0];
    stage16k(A + (size_t)m0 * K, K, b0, tid);
#pragma unroll
    for (int j = 0; j < 3; ++j)
      stage16k(Bt + (size_t)(n0 + 128 * j) * K, K, b0 + 8192 + 8192 * j, tid);
  }

#pragma unroll 1
  for (int t = 0; t < NT; ++t) {
    __syncthreads();                         // drains vmcnt(0): tile t landed (issued a full segment ago)
    const short* buf = &LDS[t & 1][0];
    short* nb = &LDS[(t & 1) ^ 1][0];
    const int kc = (t + 1) << 6;

    // ---- kk = 0: reads + stage-issue + 24 MFMA ----
    short8 a0[4], b0[6];
#pragma unroll
    for (int mi = 0; mi < 4; ++mi)
      a0[mi] = fragld2(buf, wr * 64 + mi * 16 + lq, quad);
#pragma unroll
    for (int ni = 0; ni < 6; ++ni)
      b0[ni] = fragld2(buf + 8192, wc * 96 + ni * 16 + lq, quad);
    if (t + 1 < NT) {                        // stage tile t+1 -> other buffer
      stage16k(A + (size_t)m0 * K + kc, K, nb, tid);
#pragma unroll
      for (int j = 0; j < 3; ++j)
        stage16k(Bt + (size_t)(n0 + 128 * j) * K + kc, K, nb + 8192 + 8192 * j, tid);
    }
    __builtin_amdgcn_s_setprio(1);
#pragma unroll
    for (int mi = 0; mi < 4; ++mi)
#pragma unroll
      for (int ni = 0; ni < 6; ++ni)
        acc[mi][ni] = __builtin_amdgcn_mfma_f32_16x16x32_bf16(a0[mi], b0[ni], acc[mi][ni], 0, 0, 0);
    __builtin_amdgcn_s_setprio(0);

    // ---- kk = 1: reads + 24 MFMA ----
    short8 a1[4], b1[6];
#pragma unroll
    for (int mi = 0; mi < 4; ++mi)
      a1[mi] = fragld2(buf, wr * 64 + mi * 16 + lq, 4 + quad);
#pragma unroll
    for (int ni = 0; ni < 6; ++ni)
      b1[ni] = fragld2(buf + 8192, wc * 96 + ni * 16 + lq, 4 + quad);
    __builtin_amdgcn_s_setprio(1);
#pragma unroll
    for (int mi = 0; mi < 4; ++mi)
#pragma unroll
      for (int ni = 0; ni < 6; ++ni)
        acc[mi][ni] = __builtin_amdgcn_mfma_f32_16x16x32_bf16(a1[mi], b1[ni], acc[mi][ni], 0, 0, 0);
    __builtin_amdgcn_s_setprio(0);
  }

  // epilogue: bf16 store, q-columns pre-scaled by log2e/sqrt(64)
#pragma unroll
  for (int mi = 0; mi < 4; ++mi) {
#pragma unroll
    for (int ni = 0; ni < 6; ++ni) {
      int col = n0 + wc * 96 + ni * 16 + lq;
      float sc = (col < 1024) ? qscale : 1.0f;
#pragma unroll
      for (int r = 0; r < 4; ++r) {
        int row = m0 + wr * 64 + mi * 16 + quad * 4 + r;
        Cb[(size_t)row * N + col] = __float2bfloat16(acc[mi][ni][r] * sc);
      }
    }
  }
}

// ---------------- GEMM: C = A[M,K] * Bt[N,K]^T (output projection) ----------------
template <int EPI>
__launch_bounds__(256, 2)
__global__ void gemm_bt(const __hip_bfloat16* __restrict__ A, const __hip_bfloat16* __restrict__ Bt,
                        __hip_bfloat16* __restrict__ Cb, float* __restrict__ Cf,
                        const float* __restrict__ bias, int M, int N, int K, float qscale) {
  __shared__ __hip_bfloat16 As[128 * 32];
  __shared__ __hip_bfloat16 Bs[128 * 32];
  const int tid = threadIdx.x;
  const int w = tid >> 6, lane = tid & 63;
  const int lq = lane & 15, quad = lane >> 4;
  const int wr = w >> 1, wc = w & 1;
  const int m0 = blockIdx.x * 128, n0 = blockIdx.y * 128;

  floatx4 acc[4][4];
#pragma unroll
  for (int i = 0; i < 4; i++)
#pragma unroll
    for (int j = 0; j < 4; j++) acc[i][j] = (floatx4){0.f, 0.f, 0.f, 0.f};

  for (int k0 = 0; k0 < K; k0 += 32) {
    __syncthreads();
#pragma unroll
    for (int ph = 0; ph < 2; ++ph) {
      int c = ph * 256 + tid;
      int row = c >> 2, col8 = c & 3;
      async_copy16(A + (size_t)(m0 + row) * K + k0 + col8 * 8, As + c * 8);
      async_copy16(Bt + (size_t)(n0 + row) * K + k0 + col8 * 8, Bs + c * 8);
    }
    __syncthreads();
    short8 af[4], bf[4];
#pragma unroll
    for (int mi = 0; mi < 4; mi++)
      af[mi] = *(const short8*)(As + (wr * 64 + mi * 16 + lq) * 32 + quad * 8);
#pragma unroll
    for (int ni = 0; ni < 4; ni++)
      bf[ni] = *(const short8*)(Bs + (wc * 64 + ni * 16 + lq) * 32 + quad * 8);
#pragma unroll
    for (int mi = 0; mi < 4; mi++)
#pragma unroll
      for (int ni = 0; ni < 4; ni++)
        acc[mi][ni] = __builtin_amdgcn_mfma_f32_16x16x32_bf16(af[mi], bf[ni], acc[mi][ni], 0, 0, 0);
  }

#pragma unroll
  for (int mi = 0; mi < 4; mi++) {
#pragma unroll
    for (int ni = 0; ni < 4; ni++) {
      int col = n0 + wc * 64 + ni * 16 + lq;
      if (EPI == 0) {
        float s = (col < 1024) ? qscale : 1.0f;
#pragma unroll
        for (int r = 0; r < 4; r++) {
          int row = m0 + wr * 64 + mi * 16 + quad * 4 + r;
          Cb[(size_t)row * N + col] = __float2bfloat16(acc[mi][ni][r] * s);
        }
      } else {
        float bv = bias[col];
#pragma unroll
        for (int r = 0; r < 4; r++) {
          int row = m0 + wr * 64 + mi * 16 + quad * 4 + r;
          Cf[(size_t)row * N + col] = acc[mi][ni][r] + bv;
        }
      }
    }
  }
}

// ---------------- flash attention: KVBLK=128 (2 tiles/iter), double-buffered, XCD-local ----------------
// Round-11: halve the synchronization rate. Each iteration stages and computes a
// PAIR of 64-row KV tiles (contiguous in kpack/vpack -> staging stays coalesced).
// Barriers + vmcnt waits per KV-tile halve; compute per segment ~doubles, so the
// end-of-iteration vmcnt(0) lands ~1500 cyc after issue (L2 latency fully hidden)
// without 3-buffer LDS pressure. Pairs 0..tbase/2 exactly cover tiles 0..tbase+1
// (tbase always even). Wave-uniform predicate t64<=qt; mask at t64==qt. Barriers
// unconditional. Grid (64,8) proven.
__launch_bounds__(256, 2)
__global__ void attn(const __hip_bfloat16* __restrict__ qkv,
                     const __hip_bfloat16* __restrict__ kpack,
                     const __hip_bfloat16* __restrict__ vpack,
                     __hip_bfloat16* __restrict__ obuf) {
  __shared__ __hip_bfloat16 KVs[2][16384];   // [buf][K pair 0..8191 | V pair 8192..16383], 64 KB
  const int tid = threadIdx.x;
  const int w = tid >> 6, lane = tid & 63;
  const int lq = lane & 15, quad = lane >> 4;

  const int bh = (int)blockIdx.x;            // XCD = bh % 8
  const int a  = (int)blockIdx.y;            // 0..7
  const int b = bh >> 4, h = bh & 15;

  const __hip_bfloat16* kbase = kpack + ((size_t)bh * NST) * 4096;
  const __hip_bfloat16* vbase = vpack + ((size_t)bh * NST) * 4096;

#pragma unroll 1
  for (int seg = 0; seg < 2; ++seg) {
    const int tbase = seg ? (NST - 2 - 2 * a) : (2 * a);   // even
    const int qt = tbase + (w >> 1);         // this wave's q-tile
    const int rbase = (w & 1) * 32;          // row base within tile

    short8 qf[2][2];
#pragma unroll
    for (int bi = 0; bi < 2; bi++) {
      const __hip_bfloat16* qp =
          qkv + ((size_t)(b * T_ + qt * 64 + rbase + bi * 16 + lq)) * NQKV + h * HD_;
      qf[bi][0] = *(const short8*)(qp + quad * 8);
      qf[bi][1] = *(const short8*)(qp + 32 + quad * 8);
    }

    floatx4 Oacc[2][4];
#pragma unroll
    for (int bi = 0; bi < 2; bi++)
#pragma unroll
      for (int i = 0; i < 4; i++) Oacc[bi][i] = (floatx4){0.f, 0.f, 0.f, 0.f};
    float lrow[2] = {0.f, 0.f};

    const int pTop = tbase >> 1;             // pairs 0..pTop cover tiles 0..tbase+1

    // prologue: stage pair 0 (K: 8192 elems, V: 8192 elems; 8 loads/thread)
#pragma unroll
    for (int j = 0; j < 4; ++j) {
      int c = j * 256 + tid;
      async_copy16(kbase + (size_t)c * 8, &KVs[0][0] + c * 8);
      async_copy16(vbase + (size_t)c * 8, &KVs[0][8192] + c * 8);
    }
    asm volatile("s_waitcnt vmcnt(0)" ::: "memory");
    __builtin_amdgcn_s_barrier();

    int cur = 0;
#pragma unroll 1
    for (int p = 0; p <= pTop; ++p) {
      if (p < pTop) {                        // stage pair p+1 into other buffer
        const __hip_bfloat16* kn = kbase + (size_t)(2 * (p + 1)) * 4096;
        const __hip_bfloat16* vn = vbase + (size_t)(2 * (p + 1)) * 4096;
#pragma unroll
        for (int j = 0; j < 4; ++j) {
          int c = j * 256 + tid;
          async_copy16(kn + (size_t)c * 8, &KVs[cur ^ 1][0] + c * 8);
          async_copy16(vn + (size_t)c * 8, &KVs[cur ^ 1][8192] + c * 8);
        }
      }
#pragma unroll
      for (int f = 0; f < 2; ++f) {
        const int t64 = 2 * p + f;
        if (t64 <= qt) {                     // wave-uniform predicate (no barriers inside)
          const __hip_bfloat16* Kb = &KVs[cur][f * 4096] + lane * 8;
          const __hip_bfloat16* Vb = &KVs[cur][8192 + f * 4096] + lane * 8;
          short8 kf[4], kg[4];
#pragma unroll
          for (int ni = 0; ni < 4; ni++) {
            kf[ni] = *(const short8*)(Kb + (size_t)(ni * 2 + 0) * 512);
            kg[ni] = *(const short8*)(Kb + (size_t)(ni * 2 + 1) * 512);
          }
          short8 vfr[8];
#pragma unroll
          for (int c = 0; c < 8; c++) vfr[c] = *(const short8*)(Vb + (size_t)c * 512);

          floatx4 Sc[2][4];
          __builtin_amdgcn_s_setprio(1);
#pragma unroll
          for (int bi = 0; bi < 2; bi++)
#pragma unroll
            for (int ni = 0; ni < 4; ni++) {
              floatx4 c0 = (floatx4){0.f, 0.f, 0.f, 0.f};
              c0 = __builtin_amdgcn_mfma_f32_16x16x32_bf16(kf[ni], qf[bi][0], c0, 0, 0, 0);
              c0 = __builtin_amdgcn_mfma_f32_16x16x32_bf16(kg[ni], qf[bi][1], c0, 0, 0, 0);
              Sc[bi][ni] = c0;
            }
          __builtin_amdgcn_s_setprio(0);

          if (t64 == qt) {                   // causal mask on the diagonal tile
#pragma unroll
            for (int bi = 0; bi < 2; bi++) {
              int lrow_idx = rbase + bi * 16 + lq;
#pragma unroll
              for (int ni = 0; ni < 4; ni++)
#pragma unroll
                for (int r = 0; r < 4; r++) {
                  int s_loc = ni * 16 + quad * 4 + r;
                  if (s_loc > lrow_idx) Sc[bi][ni][r] = -__builtin_inff();
                }
            }
          }

          bf16x4 pf[2][4];
#pragma unroll
          for (int bi = 0; bi < 2; bi++)
#pragma unroll
            for (int c = 0; c < 4; c++) {
              __hip_bfloat16 pb[4];
#pragma unroll
              for (int r = 0; r < 4; r++) {
                float pv = __builtin_amdgcn_exp2f(Sc[bi][c][r]);
                lrow[bi] += pv;
                pb[r] = __float2bfloat16(pv);
              }
              pf[bi][c] = *(bf16x4*)pb;
            }

          __builtin_amdgcn_s_setprio(1);
#pragma unroll
          for (int m = 0; m < 2; m++)
#pragma unroll
            for (int nt = 0; nt < 4; nt++) {
              short8 v8 = vfr[m * 4 + nt];
              bf16x4 vlo = (bf16x4){v8[0], v8[1], v8[2], v8[3]};
              bf16x4 vhi = (bf16x4){v8[4], v8[5], v8[6], v8[7]};
#pragma unroll
              for (int bi = 0; bi < 2; bi++) {
                Oacc[bi][nt] = mfma16(pf[bi][2 * m + 0], vlo, Oacc[bi][nt]);
                Oacc[bi][nt] = mfma16(pf[bi][2 * m + 1], vhi, Oacc[bi][nt]);
              }
            }
          __builtin_amdgcn_s_setprio(0);
        }
      }
      // boundary: drain next pair's loads (issued at top of this iter, ~1500 cyc ago)
      if (p < pTop) { asm volatile("s_waitcnt vmcnt(0)" ::: "memory"); }
      __builtin_amdgcn_s_barrier();
      cur ^= 1;
    }

    // epilogue per band: reduce lrow across quads, normalize, store
#pragma unroll
    for (int bi = 0; bi < 2; bi++) {
      float ps = lrow[bi];
      ps += __shfl_xor(ps, 16);
      ps += __shfl_xor(ps, 32);
      float inv = 1.0f / ps;
#pragma unroll
      for (int r = 0; r < 4; r++) {
        float invr = __shfl(inv, quad * 4 + r);
        int t = qt * 64 + rbase + bi * 16 + quad * 4 + r;
#pragma unroll
        for (int nt = 0; nt < 4; nt++)
          obuf[(size_t)(b * T_ + t) * D_ + h * HD_ + nt * 16 + lq] =
              __float2bfloat16(Oacc[bi][nt][r] * invr);
      }
    }
  }
}

// ---------------- launch ----------------

extern "C" void kernel_launch(void* const* d_in, const int* in_sizes, int n_in,
                              void* d_out, int out_size, void* d_ws, size_t ws_size,
                              hipStream_t stream) {
  const float* x  = (const float*)d_in[0];
  const float* Wq = (const float*)d_in[1];
  const float* Wk = (const float*)d_in[2];
  const float* Wv = (const float*)d_in[3];
  const float* Wo = (const float*)d_in[4];
  const float* bo = (const float*)d_in[5];
  float* out = (float*)d_out;

  char* ws = (char*)d_ws;
  __hip_bfloat16* xb    = (__hip_bfloat16*)(ws);                          // 16 MB (dead after QKV gemm)
  __hip_bfloat16* obuf  = (__hip_bfloat16*)(ws);                          // reuses xb's slot
  __hip_bfloat16* wqkv  = (__hip_bfloat16*)(ws + ((size_t)16 << 20));     //  6 MB
  __hip_bfloat16* wob   = (__hip_bfloat16*)(ws + ((size_t)22 << 20));     //  2 MB
  __hip_bfloat16* qkv   = (__hip_bfloat16*)(ws + ((size_t)24 << 20));     // 48 MB
  __hip_bfloat16* kpack = (__hip_bfloat16*)(ws + ((size_t)72 << 20));     // 16 MB
  __hip_bfloat16* vpack = (__hip_bfloat16*)(ws + ((size_t)88 << 20));     // 16 MB

  prep<<<9984, 256, 0, stream>>>(x, Wo, Wq, Wk, Wv, xb, wob, wqkv);

  // qkv = xb * wqkv^T   (q columns pre-scaled by log2e/8) — 128x384 single-segment kernel
  gemmq<<<512, 512, 0, stream>>>(xb, wqkv, qkv, MROWS, NQKV, D_, QSCALE);

  repack_kv<<<dim3(NST, B_ * H_), 256, 0, stream>>>(qkv, kpack, vpack);

  attn<<<dim3(B_ * H_, 8), 256, 0, stream>>>(qkv, kpack, vpack, obuf);

  // out = obuf * Wo^T + bo — proven gemm_bt<1>
  gemm_bt<1><<<dim3(MROWS / 128, D_ / 128), 256, 0, stream>>>(
      obuf, wob, nullptr, out, bo, MROWS, D_, D_, 1.0f);
}